// Round 4
// baseline (784.726 us; speedup 1.0000x reference)
//
#include <hip/hip_runtime.h>

typedef _Float16 half8 __attribute__((ext_vector_type(8)));
typedef _Float16 half4 __attribute__((ext_vector_type(4)));
typedef float f32x4 __attribute__((ext_vector_type(4)));
typedef int int4v __attribute__((ext_vector_type(4)));

#define ROWS 32                 // 512 blocks; target 2 blocks/CU
#define NC (ROWS / 16)
#define HP 136                  // h row pitch (halfs): 128 + 8 pad
#define HBUFSZ (ROWS * HP)
#define LOG2E 1.442695041f
#define MFMA(a,b,c) __builtin_amdgcn_mfma_f32_16x16x32_f16((a),(b),(c),0,0,0)

// ---- prep: w1 / w_ih fragments -> workspace as f16 (L2-resident) ----
__global__ void prep_frags(const float* __restrict__ w1,
                           const float* __restrict__ w_ih,
                           _Float16* __restrict__ ws)
{
    int idx = blockIdx.x * 256 + threadIdx.x;
    if (idx < 16384) {          // w1f[((kt*4+q)*128 + d)*8 + j]
        int j = idx & 7, d = (idx >> 3) & 127, fq = idx >> 10;
        int kt = fq >> 2, qq = fq & 3;
        ws[idx] = (_Float16)w1[d * 128 + kt * 32 + qq * 8 + j];
    }
    if (idx < 3072) {           // wxf[(g*128 + d)*8 + j], pre-scaled by gate
        int j = idx & 7, gd = idx >> 3, g = gd >> 7;
        float sc = (g < 2) ? -LOG2E : -2.0f * LOG2E;
        ws[16384 + idx] = (j < 6) ? (_Float16)(w_ih[gd * 6 + j] * sc) : (_Float16)0.0f;
    }
}

// Allocator model (r0-r3 evidence): cap 128 (=4 waves/EU) splits hard 64 arch
// / 64 accum. Strategy: pin Wg into AGPRs (MFMA reads A from AGPR directly),
// single-buffer everything, biases in LDS -> arch fits 64, agpr = 48+16 = 64.
__global__ __launch_bounds__(512, 4)
void traj_gru(const float* __restrict__ history,
              const float* __restrict__ w_ih, const float* __restrict__ w_hh,
              const float* __restrict__ b_ih, const float* __restrict__ b_hh,
              const float* __restrict__ w1, const float* __restrict__ b1,
              const float* __restrict__ w2, const float* __restrict__ b2,
              const _Float16* __restrict__ ws,
              float* __restrict__ out)
{
    __shared__ __align__(16) _Float16 hbuf[2 * HBUFSZ];     // 17,408 B
    __shared__ __align__(16) _Float16 xhist[50 * ROWS * 6]; // 19,200 B
    __shared__ __align__(16) _Float16 xdec[ROWS * 8];       //    512 B
    __shared__ __align__(16) _Float16 w2f[4 * 4 * 16 * 8];  //  4,096 B
    __shared__ __align__(16) float    biasf[4 * 128];       //  2,048 B => 43,264 total

    const int tid  = threadIdx.x;
    const int wave = tid >> 6;
    const int lane = tid & 63;
    const int ln16 = lane & 15;
    const int q    = lane >> 4;
    const int rowbase = blockIdx.x * ROWS;
    const int dbase = wave * 16;

    const _Float16* w1g = ws;            // head w1 frags (global, L2-hot)
    const _Float16* wxg = ws + 16384;    // gru x-weight frags

    // ---- init LDS ----
    for (int i = tid; i < 2 * HBUFSZ; i += 512) hbuf[i] = (_Float16)0;
    for (int i = tid; i < ROWS * 8; i += 512) xdec[i] = (_Float16)0;
    for (int i = tid; i < 4 * 4 * 16 * 8; i += 512) w2f[i] = (_Float16)0;
    __syncthreads();
    for (int idx = tid; idx < ROWS * 300; idx += 512) {
        int r = idx / 300, rem = idx - r * 300;
        int t = rem / 6, c = rem - t * 6;
        xhist[(t * ROWS + r) * 6 + c] = (_Float16)history[(rowbase + r) * 300 + rem];
    }
    if (tid < ROWS) xdec[tid * 8 + 6] = (_Float16)1.0f;
    for (int idx = tid; idx < 6 * 128; idx += 512) {      // w2 -> B-frag layout
        int n = idx >> 7, k = idx & 127;
        int kt = k >> 5, qq = (k >> 3) & 3, j = k & 7;
        w2f[((kt * 4 + qq) * 16 + n) * 8 + j] = (_Float16)w2[n * 128 + k];
    }
    {   // biases -> LDS f32: [0]=rr [1]=rz [2]=in(n) [3]=hn(hh), scaled
        int g = tid >> 7, d = tid & 127;
        float v;
        if      (g == 0) v = (b_ih[d]       + b_hh[d]      ) * (-LOG2E);
        else if (g == 1) v = (b_ih[128 + d] + b_hh[128 + d]) * (-LOG2E);
        else if (g == 2) v = b_ih[256 + d] * (-2.0f * LOG2E);
        else             v = b_hh[256 + d] * (-2.0f * LOG2E);
        biasf[g * 128 + d] = v;
    }

    // ---- Wg: h-weights, pinned to AGPRs (direct MFMA A-operands) ----
    half8 Wg[3][4];
    #pragma unroll
    for (int g = 0; g < 3; ++g) {
        float sc = (g < 2) ? -LOG2E : -2.0f * LOG2E;
        #pragma unroll
        for (int kt = 0; kt < 4; ++kt) {
            const float* p = w_hh + (g * 128 + dbase + ln16) * 128 + kt * 32 + q * 8;
            half8 v;
            #pragma unroll
            for (int j = 0; j < 8; ++j) v[j] = (_Float16)(p[j] * sc);
            Wg[g][kt] = v;
        }
    }
    #pragma unroll
    for (int g = 0; g < 3; ++g)
        #pragma unroll
        for (int kt = 0; kt < 4; ++kt)
            asm volatile("" : "+a"(Wg[g][kt]));   // pin to accum side of the RF

    const float b1r = b1[dbase + ln16];
    const float b2r = (ln16 < 6) ? b2[ln16] : 0.0f;

    float hp[NC][4] = {};   // h_prev: (batch=c*16+ln16, dim=dbase+q*4+i)

    __syncthreads();

    // ---- GRU step: single-buffered, 1 barrier ----
    auto gru_step = [&](int p, int t, bool enc) {
        const _Float16* hb = hbuf + p * HBUFSZ;
        _Float16*       hn = hbuf + (p ^ 1) * HBUFSZ;
        #pragma unroll
        for (int c = 0; c < NC; ++c) {
            // x-weight frags from global (L2) — issue first, consumed last
            half8 wx0 = *(const half8*)(wxg + ((0 * 128 + dbase + ln16) << 3));
            half8 wx1 = *(const half8*)(wxg + ((1 * 128 + dbase + ln16) << 3));
            half8 wx2 = *(const half8*)(wxg + ((2 * 128 + dbase + ln16) << 3));
            // h frags from LDS
            const _Float16* rp = hb + (c * 16 + ln16) * HP;
            half8 Bf0 = *(const half8*)(rp +   0 + q * 8);
            half8 Bf1 = *(const half8*)(rp +  32 + q * 8);
            half8 Bf2 = *(const half8*)(rp +  64 + q * 8);
            half8 Bf3 = *(const half8*)(rp +  96 + q * 8);
            // x vector
            half8 Bx;
            if (enc) {
                const int* xi = (const int*)xhist;
                int base = (t * ROWS + c * 16 + ln16) * 3;
                int4v dv = { xi[base], xi[base + 1], xi[base + 2], 0x3C00 };
                Bx = __builtin_bit_cast(half8, dv);
            } else {
                Bx = *(const half8*)(xdec + (c * 16 + ln16) * 8);
            }
            // acc init = biases (LDS broadcast reads)
            const int d0 = dbase + q * 4;
            f32x4 r  = *(const f32x4*)(biasf +   0 + d0);
            f32x4 z  = *(const f32x4*)(biasf + 128 + d0);
            f32x4 n  = *(const f32x4*)(biasf + 256 + d0);
            f32x4 hh = *(const f32x4*)(biasf + 384 + d0);
            const half8 zero8 = {};
            half8 m0 = (q == 0) ? wx0 : zero8;
            half8 m1 = (q == 0) ? wx1 : zero8;
            half8 m2 = (q == 0) ? wx2 : zero8;
            r  = MFMA(Wg[0][0], Bf0, r);  z  = MFMA(Wg[1][0], Bf0, z);  hh = MFMA(Wg[2][0], Bf0, hh);
            r  = MFMA(Wg[0][1], Bf1, r);  z  = MFMA(Wg[1][1], Bf1, z);  hh = MFMA(Wg[2][1], Bf1, hh);
            r  = MFMA(Wg[0][2], Bf2, r);  z  = MFMA(Wg[1][2], Bf2, z);  hh = MFMA(Wg[2][2], Bf2, hh);
            r  = MFMA(Wg[0][3], Bf3, r);  z  = MFMA(Wg[1][3], Bf3, z);  hh = MFMA(Wg[2][3], Bf3, hh);
            r  = MFMA(m0, Bx, r);
            z  = MFMA(m1, Bx, z);
            n  = MFMA(m2, Bx, n);
            // gates
            half4 hv;
            #pragma unroll
            for (int i = 0; i < 4; ++i) {
                float rr = __builtin_amdgcn_rcpf(1.0f + __builtin_amdgcn_exp2f(r[i]));
                float zz = __builtin_amdgcn_rcpf(1.0f + __builtin_amdgcn_exp2f(z[i]));
                float tt = n[i] + rr * hh[i];
                float nn = 2.0f * __builtin_amdgcn_rcpf(1.0f + __builtin_amdgcn_exp2f(tt)) - 1.0f;
                float h = nn + zz * (hp[c][i] - nn);
                hp[c][i] = h;
                hv[i] = (_Float16)h;
            }
            *(half4*)(hn + (c * 16 + ln16) * HP + dbase + q * 4) = hv;
        }
        __syncthreads();
    };

    // ---- head step: w1 frags from global; phase-2 byte-identical to r2 ----
    auto head_step = [&](int f, int p) {
        const int sw   = ln16 & 3;
        const int bblk = wave >> 1;
        const int colin = ((wave & 1) << 4) | ln16;
        const _Float16* hb = hbuf + p * HBUFSZ;
        _Float16*       a1 = hbuf + (p ^ 1) * HBUFSZ;   // dead ping-pong half
        #pragma unroll
        for (int c = 0; c < NC; ++c) {
            half8 Bw0 = *(const half8*)(w1g + ((0 * 4 + q) * 128 + dbase + ln16) * 8);
            half8 Bw1 = *(const half8*)(w1g + ((1 * 4 + q) * 128 + dbase + ln16) * 8);
            half8 Bw2 = *(const half8*)(w1g + ((2 * 4 + q) * 128 + dbase + ln16) * 8);
            half8 Bw3 = *(const half8*)(w1g + ((3 * 4 + q) * 128 + dbase + ln16) * 8);
            const _Float16* rp = hb + (c * 16 + ln16) * HP;
            half8 Ah0 = *(const half8*)(rp +   0 + q * 8);
            half8 Ah1 = *(const half8*)(rp +  32 + q * 8);
            half8 Ah2 = *(const half8*)(rp +  64 + q * 8);
            half8 Ah3 = *(const half8*)(rp +  96 + q * 8);
            f32x4 a = {0,0,0,0};
            a = MFMA(Ah0, Bw0, a);
            a = MFMA(Ah1, Bw1, a);
            a = MFMA(Ah2, Bw2, a);
            a = MFMA(Ah3, Bw3, a);
            #pragma unroll
            for (int i = 0; i < 4; ++i) {
                float v = a[i] + b1r;
                v = v > 0.0f ? v : 0.0f;
                a1[(c * 16 + q * 4 + i) * HP + ((bblk ^ i) << 5) + colin] = (_Float16)v;
            }
        }
        __syncthreads();
        if (wave < NC) {   // phase 2: A=a1 (m=batch), B=w2f (n=out-dim)
            const _Float16* rp = a1 + (wave * 16 + ln16) * HP;
            f32x4 o = {0,0,0,0};
            #pragma unroll
            for (int kt = 0; kt < 4; ++kt) {
                half8 Aa = *(const half8*)(rp + ((kt ^ sw) << 5) + q * 8);
                half8 Bw = *(const half8*)&w2f[((kt * 4 + q) * 16 + ln16) * 8];
                o = MFMA(Aa, Bw, o);
            }
            if (ln16 < 6) {
                #pragma unroll
                for (int i = 0; i < 4; ++i) {
                    int row = wave * 16 + q * 4 + i;
                    float v = o[i] + b2r;
                    out[(rowbase + row) * 180 + f * 6 + ln16] = v;
                    xdec[row * 8 + ln16] = (_Float16)v;
                }
            }
        }
        __syncthreads();
    };

    int p = 0;
    #pragma unroll 1
    for (int t = 0; t < 50; ++t) { gru_step(p, t, true); p ^= 1; }
    #pragma unroll 1
    for (int f = 0; f < 30; ++f) {
        gru_step(p, f == 0 ? 49 : 0, f == 0);
        p ^= 1;
        head_step(f, p);
    }
}

extern "C" void kernel_launch(void* const* d_in, const int* in_sizes, int n_in,
                              void* d_out, int out_size, void* d_ws, size_t ws_size,
                              hipStream_t stream) {
    (void)in_sizes; (void)n_in; (void)ws_size; (void)out_size;
    _Float16* ws = (_Float16*)d_ws;
    prep_frags<<<dim3(64), dim3(256), 0, stream>>>(
        (const float*)d_in[5], (const float*)d_in[1], ws);
    traj_gru<<<dim3(16384 / ROWS), dim3(512), 0, stream>>>(
        (const float*)d_in[0], (const float*)d_in[1], (const float*)d_in[2],
        (const float*)d_in[3], (const float*)d_in[4], (const float*)d_in[5],
        (const float*)d_in[6], (const float*)d_in[7], (const float*)d_in[8],
        ws, (float*)d_out);
}

// Round 5
// 288.173 us; speedup vs baseline: 2.7231x; 2.7231x over previous
//
#include <hip/hip_runtime.h>

typedef _Float16 half8 __attribute__((ext_vector_type(8)));
typedef _Float16 half4 __attribute__((ext_vector_type(4)));
typedef float f32x4 __attribute__((ext_vector_type(4)));

#define ROWS 64
#define HP 136                  // h row pitch (halfs): 128 + 8 pad; 272 B
#define HBUFSZ (ROWS * HP)
#define LOG2E 1.442695041f
#define MFMA(a,b,c) __builtin_amdgcn_mfma_f32_16x16x32_f16((a),(b),(c),0,0,0)

// r0 structure (proven 234us, VGPR 100, 1 block/CU). Occupancy pushes (r1-r4)
// all failed: cap-128 imposes a hard 64/64 arch/acc split -> spills. This
// round: within-block pipe overlap via s_setprio around MFMA bursts (T5) +
// encoder x as single ds_read_b128 (xhist padded to 8 halfs/row).
__global__ __launch_bounds__(512, 2)
void traj_gru(const float* __restrict__ history,
              const float* __restrict__ w_ih, const float* __restrict__ w_hh,
              const float* __restrict__ b_ih, const float* __restrict__ b_hh,
              const float* __restrict__ w1, const float* __restrict__ b1,
              const float* __restrict__ w2, const float* __restrict__ b2,
              float* __restrict__ out)
{
    __shared__ __align__(16) _Float16 hbuf[2 * HBUFSZ];     // 34,816 B; a1 aliases dead half
    __shared__ __align__(16) _Float16 xhist[50 * ROWS * 8]; // 51,200 B [t][row][8] (x0..x5,1,0)
    __shared__ __align__(16) _Float16 xdec[ROWS * 8];       //  1,024 B
    __shared__ __align__(16) _Float16 w2f[4 * 4 * 16 * 8];  //  4,096 B => 91,136 total

    const int tid  = threadIdx.x;
    const int wave = tid >> 6;
    const int lane = tid & 63;
    const int ln16 = lane & 15;
    const int q    = lane >> 4;
    const int sw   = ln16 & 3;               // head-phase2 a1s read swizzle (round-7 pair)
    const int rowbase = blockIdx.x * ROWS;
    const int dbase = wave * 16;             // gru: wave's h-dims; head: wave's a1-dims
    const int bblk  = wave >> 1;             // head a1s write swizzle (round-7 pair)
    const int colin = ((wave & 1) << 4) | ln16;

    // ---- init LDS: zeros first, barrier, then fills ----
    for (int i = tid; i < 2 * HBUFSZ; i += 512) hbuf[i] = (_Float16)0;
    for (int i = tid; i < ROWS * 8; i += 512) xdec[i] = (_Float16)0;
    for (int i = tid; i < 4 * 4 * 16 * 8; i += 512) w2f[i] = (_Float16)0;
    __syncthreads();
    for (int idx = tid; idx < 50 * ROWS * 8; idx += 512) {  // [t][row][8]: x0..x5, 1.0, 0.0
        int c = idx & 7, tr = idx >> 3;
        int r = tr & (ROWS - 1), t = tr >> 6;
        _Float16 v;
        if (c < 6)       v = (_Float16)history[(rowbase + r) * 300 + t * 6 + c];
        else if (c == 6) v = (_Float16)1.0f;   // bias slot
        else             v = (_Float16)0.0f;
        xhist[idx] = v;
    }
    if (tid < ROWS) xdec[tid * 8 + 6] = (_Float16)1.0f;   // decoder bias slot
    for (int idx = tid; idx < 6 * 128; idx += 512) {      // w2 -> B-frag layout (round-7)
        int n = idx >> 7, k = idx & 127;
        int kt = k >> 5, qq = (k >> 3) & 3, j = k & 7;
        w2f[((kt * 4 + qq) * 16 + n) * 8 + j] = (_Float16)w2[n * 128 + k];
    }

    // ---- persistent register fragments ----
    // GRU (transposed): A-side = weights, m=ln16 -> dim dbase+ln16, k=kt*32+q*8+j
    // r,z pre-scaled by -log2e (sigmoid = rcp(1+exp2)); n by -2log2e (tanh = 2rcp-1)
    half8 Wg[3][4];
    #pragma unroll
    for (int g = 0; g < 3; ++g) {
        float sc = (g < 2) ? -LOG2E : -2.0f * LOG2E;
        #pragma unroll
        for (int kt = 0; kt < 4; ++kt) {
            const float* p = w_hh + (g * 128 + dbase + ln16) * 128 + kt * 32 + q * 8;
            half8 v;
            #pragma unroll
            for (int j = 0; j < 8; ++j) v[j] = (_Float16)(p[j] * sc);
            Wg[g][kt] = v;
        }
    }
    half8 Wx[3];     // A-side x-weights: q==0 rows k<6; bias via acc init
    #pragma unroll
    for (int g = 0; g < 3; ++g) {
        float sc = (g < 2) ? -LOG2E : -2.0f * LOG2E;
        half8 v;
        #pragma unroll
        for (int j = 0; j < 8; ++j) v[j] = (_Float16)0.0f;
        if (q == 0) {
            #pragma unroll
            for (int j = 0; j < 6; ++j) v[j] = (_Float16)(w_ih[(g * 128 + dbase + ln16) * 6 + j] * sc);
        }
        Wx[g] = v;
    }
    // gru biases -> acc init, element i -> C row = dim dbase+q*4+i
    f32x4 brr, brz, bin, bhn;
    #pragma unroll
    for (int i = 0; i < 4; ++i) {
        int d = dbase + q * 4 + i;
        brr[i] = (b_ih[d]       + b_hh[d]      ) * (-LOG2E);
        brz[i] = (b_ih[128 + d] + b_hh[128 + d]) * (-LOG2E);
        bin[i] = b_ih[256 + d] * (-2.0f * LOG2E);
        bhn[i] = b_hh[256 + d] * (-2.0f * LOG2E);
    }
    // HEAD (round-7 orientation): B-side w1, n=ln16 -> a1-dim dbase+ln16
    half8 Bw1[4];
    #pragma unroll
    for (int kt = 0; kt < 4; ++kt) {
        const float* p = w1 + (dbase + ln16) * 128 + kt * 32 + q * 8;
        half8 v;
        #pragma unroll
        for (int j = 0; j < 8; ++j) v[j] = (_Float16)p[j];
        Bw1[kt] = v;
    }
    const float b1r = b1[dbase + ln16];
    const float b2r = (ln16 < 6) ? b2[ln16] : 0.0f;

    float hp[4][4] = {};  // h_prev: lane holds (batch=c*16+ln16, dim=dbase+q*4+i)

    __syncthreads();

    // ---- transposed GRU step: C[dim][batch], contiguous half4 h-writes ----
    auto gru_step = [&](int p, int t, bool enc) {
        const _Float16* hb = hbuf + p * HBUFSZ;
        _Float16*       hn = hbuf + (p ^ 1) * HBUFSZ;
        half8 Bf[2][4], Bx[2];
        f32x4 ar[2], az[2], ahh[2], an[2];

        auto loadB = [&](int c, int buf) {
            const _Float16* rp = hb + (c * 16 + ln16) * HP;
            #pragma unroll
            for (int kt = 0; kt < 4; ++kt)
                Bf[buf][kt] = *(const half8*)(rp + kt * 32 + q * 8);
            if (enc) {   // single b128: [x0..x5, 1.0, 0.0] pre-packed at init
                Bx[buf] = *(const half8*)(xhist + ((t * ROWS + c * 16 + ln16) << 3));
            } else {
                Bx[buf] = *(const half8*)(xdec + (c * 16 + ln16) * 8);      // broadcast
            }
        };
        auto mfmas = [&](int buf) {
            f32x4 r = brr, z = brz, hh = bhn, n = bin;
            __builtin_amdgcn_s_setprio(1);   // T5: win arbitration during MFMA burst
            #pragma unroll
            for (int kt = 0; kt < 4; ++kt) {
                r  = MFMA(Wg[0][kt], Bf[buf][kt], r);
                z  = MFMA(Wg[1][kt], Bf[buf][kt], z);
                hh = MFMA(Wg[2][kt], Bf[buf][kt], hh);
            }
            r = MFMA(Wx[0], Bx[buf], r);
            z = MFMA(Wx[1], Bx[buf], z);
            n = MFMA(Wx[2], Bx[buf], n);
            __builtin_amdgcn_s_setprio(0);
            ar[buf] = r; az[buf] = z; ahh[buf] = hh; an[buf] = n;
        };
        auto gates = [&](int c, int cb) {
            half4 hv;
            #pragma unroll
            for (int i = 0; i < 4; ++i) {
                float r = __builtin_amdgcn_rcpf(1.0f + __builtin_amdgcn_exp2f(ar[cb][i]));
                float z = __builtin_amdgcn_rcpf(1.0f + __builtin_amdgcn_exp2f(az[cb][i]));
                float tt = an[cb][i] + r * ahh[cb][i];
                float n = 2.0f * __builtin_amdgcn_rcpf(1.0f + __builtin_amdgcn_exp2f(tt)) - 1.0f;
                float h = n + z * (hp[c][i] - n);
                hp[c][i] = h;
                hv[i] = (_Float16)h;
            }
            *(half4*)(hn + (c * 16 + ln16) * HP + dbase + q * 4) = hv;
        };

        loadB(0, 0); mfmas(0);
        #pragma unroll
        for (int c = 0; c < 4; ++c) {
            const int cb = c & 1;
            if (c < 3) { loadB(c + 1, cb ^ 1); mfmas(cb ^ 1); }
            gates(c, cb);
        }
        __syncthreads();
    };

    // ---- head step: byte-for-byte round-7 (verified), h read is plain layout ----
    auto head_step = [&](int f, int p) {
        const _Float16* hb = hbuf + p * HBUFSZ;
        _Float16*       a1 = hbuf + (p ^ 1) * HBUFSZ;   // dead ping-pong half
        half8 Ah[2][4];
        f32x4 aa[2];
        auto loadA = [&](int c, int buf) {
            const _Float16* rp = hb + (c * 16 + ln16) * HP;
            #pragma unroll
            for (int kt = 0; kt < 4; ++kt)
                Ah[buf][kt] = *(const half8*)(rp + kt * 32 + q * 8);   // plain [batch][dim]
        };
        auto mfh = [&](int buf) {
            f32x4 a = {0,0,0,0};
            __builtin_amdgcn_s_setprio(1);
            #pragma unroll
            for (int kt = 0; kt < 4; ++kt) a = MFMA(Ah[buf][kt], Bw1[kt], a);
            __builtin_amdgcn_s_setprio(0);
            aa[buf] = a;
        };
        auto relu4 = [&](int c, int cb) {
            #pragma unroll
            for (int i = 0; i < 4; ++i) {
                float v = aa[cb][i] + b1r;
                v = v > 0.0f ? v : 0.0f;
                a1[(c * 16 + q * 4 + i) * HP + ((bblk ^ i) << 5) + colin] = (_Float16)v;
            }
        };
        loadA(0, 0); mfh(0);
        #pragma unroll
        for (int c = 0; c < 4; ++c) {
            const int cb = c & 1;
            if (c < 3) { loadA(c + 1, cb ^ 1); mfh(cb ^ 1); }
            relu4(c, cb);
        }
        __syncthreads();
        if (wave < 4) {   // round-7 phase 2: A=a1 (m=batch), B=w2f (n=out-dim)
            const _Float16* rp = a1 + (wave * 16 + ln16) * HP;
            f32x4 o = {0,0,0,0};
            #pragma unroll
            for (int kt = 0; kt < 4; ++kt) {
                half8 Aa = *(const half8*)(rp + ((kt ^ sw) << 5) + q * 8);
                half8 Bw = *(const half8*)&w2f[((kt * 4 + q) * 16 + ln16) * 8];
                o = MFMA(Aa, Bw, o);
            }
            if (ln16 < 6) {
                #pragma unroll
                for (int i = 0; i < 4; ++i) {
                    int row = wave * 16 + q * 4 + i;
                    float v = o[i] + b2r;
                    out[(rowbase + row) * 180 + f * 6 + ln16] = v;
                    xdec[row * 8 + ln16] = (_Float16)v;   // next decoder x (slots 0..5)
                }
            }
        }
        __syncthreads();
    };

    int p = 0;
    #pragma unroll 1
    for (int t = 0; t < 50; ++t) { gru_step(p, t, true); p ^= 1; }
    #pragma unroll 1
    for (int f = 0; f < 30; ++f) {
        gru_step(p, f == 0 ? 49 : 0, f == 0);   // f=0: x = history[:,49]
        p ^= 1;
        head_step(f, p);
    }
}

extern "C" void kernel_launch(void* const* d_in, const int* in_sizes, int n_in,
                              void* d_out, int out_size, void* d_ws, size_t ws_size,
                              hipStream_t stream) {
    (void)in_sizes; (void)n_in; (void)d_ws; (void)ws_size; (void)out_size;
    traj_gru<<<dim3(16384 / ROWS), dim3(512), 0, stream>>>(
        (const float*)d_in[0], (const float*)d_in[1], (const float*)d_in[2],
        (const float*)d_in[3], (const float*)d_in[4], (const float*)d_in[5],
        (const float*)d_in[6], (const float*)d_in[7], (const float*)d_in[8],
        (float*)d_out);
}